// Round 1
// baseline (354.116 us; speedup 1.0000x reference)
//
#include <hip/hip_runtime.h>

#define BB 8
#define NN 4096
#define TI 32
#define NTHREADS 256
#define NBLK_PER_B (NN / TI)   // 128

// ws layout (floats):
//   q:     [BB*NN*3]   at offset 0
//   neigh: [BB*NN*3]   at offset BB*NN*3
//   deg:   [BB*NN]     at offset 2*BB*NN*3
// total = 229376 floats = 896 KiB

__global__ __launch_bounds__(256) void k_init(const float* __restrict__ p1,
                                              const float* __restrict__ p2,
                                              float* __restrict__ q,
                                              float* __restrict__ deg,
                                              float* __restrict__ out) {
    int i = blockIdx.x * blockDim.x + threadIdx.x;
    const int nq = BB * NN * 3;
    if (i < nq) q[i] = p2[i] - p1[i];
    if (i < BB * NN) deg[i] = 0.0f;
    if (i == 0) out[0] = 0.0f;
}

__global__ __launch_bounds__(NTHREADS) void k_main(const float* __restrict__ A,
                                                   const float* __restrict__ q,
                                                   float* __restrict__ neigh,
                                                   float* __restrict__ deg) {
    __shared__ float qs[NN * 3];        // 48 KiB: q[b] staged once
    __shared__ float red[4][TI * 3];    // cross-wave reduction scratch

    const int blk  = blockIdx.x;
    const int b    = blk / NBLK_PER_B;
    const int iblk = blk % NBLK_PER_B;
    const int i0   = iblk * TI;
    const int tid  = threadIdx.x;

    // stage q[b] (12288 floats) into LDS, coalesced
    const float* qb = q + (size_t)b * NN * 3;
    for (int idx = tid; idx < NN * 3; idx += NTHREADS) qs[idx] = qb[idx];
    __syncthreads();

    float nacc[TI][3];
#pragma unroll
    for (int i = 0; i < TI; ++i) {
        nacc[i][0] = 0.0f; nacc[i][1] = 0.0f; nacc[i][2] = 0.0f;
    }

    const float4* Ab   = (const float4*)(A + (size_t)b * NN * NN);
    float*        degb = deg + (size_t)b * NN;

    // 4 column groups; each thread owns 4 consecutive columns per group
#pragma unroll
    for (int g = 0; g < NN / (4 * NTHREADS); ++g) {
        const int j0 = g * NTHREADS * 4 + tid * 4;

        float qv[4][3];
#pragma unroll
        for (int jj = 0; jj < 4; ++jj) {
            qv[jj][0] = qs[(j0 + jj) * 3 + 0];
            qv[jj][1] = qs[(j0 + jj) * 3 + 1];
            qv[jj][2] = qs[(j0 + jj) * 3 + 2];
        }

        float dg0 = 0.f, dg1 = 0.f, dg2 = 0.f, dg3 = 0.f;
#pragma unroll
        for (int i = 0; i < TI; ++i) {
            const float4 a = Ab[(size_t)(i0 + i) * (NN / 4) + (j0 >> 2)];
            dg0 += a.x; dg1 += a.y; dg2 += a.z; dg3 += a.w;
            nacc[i][0] += a.x * qv[0][0] + a.y * qv[1][0] + a.z * qv[2][0] + a.w * qv[3][0];
            nacc[i][1] += a.x * qv[0][1] + a.y * qv[1][1] + a.z * qv[2][1] + a.w * qv[3][1];
            nacc[i][2] += a.x * qv[0][2] + a.y * qv[1][2] + a.z * qv[2][2] + a.w * qv[3][2];
        }
        atomicAdd(&degb[j0 + 0], dg0);
        atomicAdd(&degb[j0 + 1], dg1);
        atomicAdd(&degb[j0 + 2], dg2);
        atomicAdd(&degb[j0 + 3], dg3);
    }

    // block-reduce nacc (96 values) across 256 threads
    const int lane = tid & 63;
    const int wave = tid >> 6;
#pragma unroll
    for (int i = 0; i < TI; ++i) {
#pragma unroll
        for (int d = 0; d < 3; ++d) {
            float v = nacc[i][d];
#pragma unroll
            for (int s = 32; s > 0; s >>= 1) v += __shfl_down(v, s, 64);
            if (lane == 0) red[wave][i * 3 + d] = v;
        }
    }
    __syncthreads();
    if (tid < TI * 3) {
        const float v = red[0][tid] + red[1][tid] + red[2][tid] + red[3][tid];
        neigh[(size_t)b * NN * 3 + (size_t)i0 * 3 + tid] = v;
    }
}

__global__ __launch_bounds__(256) void k_final(const float* __restrict__ q,
                                               const float* __restrict__ neigh,
                                               const float* __restrict__ deg,
                                               float* __restrict__ out) {
    __shared__ float red[4];
    const int idx = blockIdx.x * blockDim.x + threadIdx.x;  // over BB*NN rows
    float s = 0.0f;
    if (idx < BB * NN) {
        const float inv = 1.0f / deg[idx];
#pragma unroll
        for (int d = 0; d < 3; ++d) {
            const float c = q[idx * 3 + d] - neigh[idx * 3 + d] * inv;
            s += c * c;
        }
    }
    const int lane = threadIdx.x & 63;
    const int wave = threadIdx.x >> 6;
#pragma unroll
    for (int sft = 32; sft > 0; sft >>= 1) s += __shfl_down(s, sft, 64);
    if (lane == 0) red[wave] = s;
    __syncthreads();
    if (threadIdx.x == 0) {
        atomicAdd(out, red[0] + red[1] + red[2] + red[3]);
    }
}

extern "C" void kernel_launch(void* const* d_in, const int* in_sizes, int n_in,
                              void* d_out, int out_size, void* d_ws, size_t ws_size,
                              hipStream_t stream) {
    const float* pred1 = (const float*)d_in[0];
    const float* pred2 = (const float*)d_in[1];
    const float* A     = (const float*)d_in[2];
    float* out = (float*)d_out;

    float* q     = (float*)d_ws;
    float* neigh = q + (size_t)BB * NN * 3;
    float* deg   = neigh + (size_t)BB * NN * 3;

    // K0: q = pred2 - pred1; zero deg and out
    {
        const int total = BB * NN * 3;
        k_init<<<(total + 255) / 256, 256, 0, stream>>>(pred1, pred2, q, deg, out);
    }
    // K1: one pass over A -> neigh (exact) + deg (atomic column sums)
    k_main<<<BB * NBLK_PER_B, NTHREADS, 0, stream>>>(A, q, neigh, deg);
    // K2: loss = sum((q - neigh/deg)^2)
    k_final<<<(BB * NN + 255) / 256, 256, 0, stream>>>(q, neigh, deg, out);
}

// Round 2
// 155.297 us; speedup vs baseline: 2.2802x; 2.2802x over previous
//
#include <hip/hip_runtime.h>

#define BB 8
#define NN 4096
#define TPB 256
#define WAVES 4
#define RPW 8                    // rows per wave
#define TI (WAVES * RPW)         // 32 rows per block
#define NRB (NN / TI)            // 128 row-blocks per batch
#define NGRP (NN / 256)          // 16 column groups of 256 cols

// ws layout (floats):
//   q:     [BB*NN*3]                 offset 0
//   neigh: [BB*NN*3]                 offset 98304
//   degp:  [BB*NRB*NN] (or [BB*NN])  offset 196608
// partial mode total: 17,563,648 bytes

__global__ __launch_bounds__(256) void k_init(const float* __restrict__ p1,
                                              const float* __restrict__ p2,
                                              float* __restrict__ q,
                                              float* __restrict__ deg_atomic,
                                              float* __restrict__ out,
                                              int atomic_mode) {
    int i = blockIdx.x * 256 + threadIdx.x;
    if (i < BB * NN * 3) q[i] = p2[i] - p1[i];
    if (atomic_mode && i < BB * NN) deg_atomic[i] = 0.0f;
    if (i == 0) out[0] = 0.0f;
}

__global__ __launch_bounds__(256, 4) void k_main(const float* __restrict__ A,
                                                 const float* __restrict__ q,
                                                 float* __restrict__ neigh,
                                                 float* __restrict__ degp,
                                                 int atomic_mode) {
    // deg accumulator, layout [comp jj][col>>2] so ds_add addresses are
    // bank-conflict-free (lane l hits bank l%32)
    __shared__ float dlds[NN];   // 16 KiB

    const int tid  = threadIdx.x;
    const int lane = tid & 63;
    const int w    = tid >> 6;
    const int b    = blockIdx.x / NRB;
    const int rb   = blockIdx.x % NRB;
    const int ro   = rb * TI + w * RPW;   // this wave's first row

#pragma unroll
    for (int k = 0; k < NN / TPB; ++k) dlds[tid + k * TPB] = 0.0f;
    __syncthreads();

    const float* Ab = A + (size_t)b * NN * NN;
    const float* qb = q + (size_t)b * NN * 3;

    float nacc[RPW][3];
#pragma unroll
    for (int r = 0; r < RPW; ++r) {
        nacc[r][0] = 0.0f; nacc[r][1] = 0.0f; nacc[r][2] = 0.0f;
    }

#pragma unroll 2
    for (int g = 0; g < NGRP; ++g) {
        const int jc = g * 256 + lane * 4;   // this lane's 4 columns
        // q for cols jc..jc+3: 12 contiguous floats (16B aligned since jc%4==0)
        const float4 q0 = *(const float4*)(qb + (size_t)jc * 3);
        const float4 q1 = *(const float4*)(qb + (size_t)jc * 3 + 4);
        const float4 q2 = *(const float4*)(qb + (size_t)jc * 3 + 8);
        // col0=(q0.x,q0.y,q0.z) col1=(q0.w,q1.x,q1.y) col2=(q1.z,q1.w,q2.x) col3=(q2.y,q2.z,q2.w)

        float dg0 = 0.f, dg1 = 0.f, dg2 = 0.f, dg3 = 0.f;
#pragma unroll
        for (int r = 0; r < RPW; ++r) {
            const float4 a = *(const float4*)(Ab + (size_t)(ro + r) * NN + jc);
            dg0 += a.x; dg1 += a.y; dg2 += a.z; dg3 += a.w;
            nacc[r][0] += a.x * q0.x + a.y * q0.w + a.z * q1.z + a.w * q2.y;
            nacc[r][1] += a.x * q0.y + a.y * q1.x + a.z * q1.w + a.w * q2.z;
            nacc[r][2] += a.x * q0.z + a.y * q1.y + a.z * q2.x + a.w * q2.w;
        }
        const int j4 = jc >> 2;              // 0..1023
        atomicAdd(&dlds[0 * 1024 + j4], dg0);
        atomicAdd(&dlds[1 * 1024 + j4], dg1);
        atomicAdd(&dlds[2 * 1024 + j4], dg2);
        atomicAdd(&dlds[3 * 1024 + j4], dg3);
    }

    // reduce nacc (24 values) across the wave's 64 lanes
    float myval = 0.0f;
#pragma unroll
    for (int r = 0; r < RPW; ++r) {
#pragma unroll
        for (int d = 0; d < 3; ++d) {
            float v = nacc[r][d];
#pragma unroll
            for (int s = 1; s < 64; s <<= 1) v += __shfl_xor(v, s, 64);
            if (lane == r * 3 + d) myval = v;
        }
    }
    if (lane < RPW * 3) {
        // neigh[b][ro+r][d] flat = (b*NN+ro)*3 + (r*3+d) = base + lane
        neigh[((size_t)b * NN + ro) * 3 + lane] = myval;
    }

    __syncthreads();
    if (atomic_mode) {
        float* dg = degp + (size_t)b * NN;
#pragma unroll
        for (int k = 0; k < NN / TPB; ++k) {
            const int col = tid + k * TPB;
            atomicAdd(&dg[col], dlds[(col & 3) * 1024 + (col >> 2)]);
        }
    } else {
        float* dg = degp + ((size_t)b * NRB + rb) * NN;
#pragma unroll
        for (int k = 0; k < NN / TPB; ++k) {
            const int col = tid + k * TPB;
            dg[col] = dlds[(col & 3) * 1024 + (col >> 2)];
        }
    }
}

__global__ __launch_bounds__(256) void k_final(const float* __restrict__ q,
                                               const float* __restrict__ neigh,
                                               const float* __restrict__ degp,
                                               int nslab,
                                               float* __restrict__ out) {
    __shared__ float red[4];
    const int idx = blockIdx.x * 256 + threadIdx.x;   // row index over BB*NN
    const int b = idx / NN;
    const int i = idx - b * NN;

    const float* dp = degp + ((size_t)b * nslab) * NN + i;
    float a0 = 0.f, a1 = 0.f, a2 = 0.f, a3 = 0.f;
    int s = 0;
    for (; s + 3 < nslab; s += 4) {
        a0 += dp[(size_t)(s + 0) * NN];
        a1 += dp[(size_t)(s + 1) * NN];
        a2 += dp[(size_t)(s + 2) * NN];
        a3 += dp[(size_t)(s + 3) * NN];
    }
    for (; s < nslab; ++s) a0 += dp[(size_t)s * NN];
    const float deg = (a0 + a1) + (a2 + a3);

    const float inv = 1.0f / deg;
    float acc = 0.0f;
#pragma unroll
    for (int d = 0; d < 3; ++d) {
        const float c = q[(size_t)idx * 3 + d] - neigh[(size_t)idx * 3 + d] * inv;
        acc += c * c;
    }

    const int lane = threadIdx.x & 63;
    const int wv   = threadIdx.x >> 6;
#pragma unroll
    for (int sft = 32; sft > 0; sft >>= 1) acc += __shfl_down(acc, sft, 64);
    if (lane == 0) red[wv] = acc;
    __syncthreads();
    if (threadIdx.x == 0) atomicAdd(out, red[0] + red[1] + red[2] + red[3]);
}

extern "C" void kernel_launch(void* const* d_in, const int* in_sizes, int n_in,
                              void* d_out, int out_size, void* d_ws, size_t ws_size,
                              hipStream_t stream) {
    const float* pred1 = (const float*)d_in[0];
    const float* pred2 = (const float*)d_in[1];
    const float* A     = (const float*)d_in[2];
    float* out = (float*)d_out;

    float* q     = (float*)d_ws;
    float* neigh = q + (size_t)BB * NN * 3;
    float* degp  = neigh + (size_t)BB * NN * 3;

    const size_t need_partial =
        ((size_t)BB * NN * 3 * 2 + (size_t)BB * NRB * NN) * sizeof(float);
    const int atomic_mode = (ws_size < need_partial) ? 1 : 0;
    const int nslab = atomic_mode ? 1 : NRB;

    {
        const int total = BB * NN * 3;
        k_init<<<(total + 255) / 256, 256, 0, stream>>>(pred1, pred2, q, degp, out,
                                                        atomic_mode);
    }
    k_main<<<BB * NRB, TPB, 0, stream>>>(A, q, neigh, degp, atomic_mode);
    k_final<<<(BB * NN) / 256, 256, 0, stream>>>(q, neigh, degp, nslab, out);
}